// Round 7
// baseline (714.861 us; speedup 1.0000x reference)
//
#include <hip/hip_runtime.h>
#include <math.h>

#define S_LEN 1024
#define I_DIM 1024
#define DH_   256
#define H_NUM 4
#define B_NUM 8
#define ROWS  (B_NUM*S_LEN)   // 8192

#define GLOBAL_AS __attribute__((address_space(1)))
#define LDS_AS    __attribute__((address_space(3)))

#define VM0    asm volatile("s_waitcnt vmcnt(0)" ::: "memory")
#define LGKM0  asm volatile("s_waitcnt lgkmcnt(0)" ::: "memory")
#define BAR    __builtin_amdgcn_s_barrier()
#define SFENCE __builtin_amdgcn_sched_barrier(0)

typedef __attribute__((ext_vector_type(8))) short bf16x8;
typedef __attribute__((ext_vector_type(4))) float f32x4;
typedef unsigned short u16;

__device__ __forceinline__ u16 f2bf(float f) {
    union { float f; unsigned u; } v; v.f = f;
    unsigned r = v.u + 0x7FFF + ((v.u >> 16) & 1);
    return (u16)(r >> 16);
}
__device__ __forceinline__ float bf2f(u16 h) {
    union { unsigned u; float f; } v; v.u = ((unsigned)h) << 16;
    return v.f;
}

// ---------------- fused LayerNorm -> bf16 ----------------
__global__ __launch_bounds__(64) void ln_fused_k(const float* __restrict__ x,
                                                 const float* __restrict__ g,
                                                 const float* __restrict__ b,
                                                 u16* __restrict__ out) {
    int row = blockIdx.x, lane = threadIdx.x;
    const float* xr = x + (size_t)row * 512;
    float4 a = *(const float4*)&xr[lane * 8];
    float4 c = *(const float4*)&xr[lane * 8 + 4];
    float s  = a.x + a.y + a.z + a.w + c.x + c.y + c.z + c.w;
    float s2 = a.x*a.x + a.y*a.y + a.z*a.z + a.w*a.w
             + c.x*c.x + c.y*c.y + c.z*c.z + c.w*c.w;
#pragma unroll
    for (int off = 32; off > 0; off >>= 1) {
        s  += __shfl_down(s, off);
        s2 += __shfl_down(s2, off);
    }
    s = __shfl(s, 0); s2 = __shfl(s2, 0);
    float mu = s * (1.f / 512.f);
    float rstd = rsqrtf(s2 * (1.f / 512.f) - mu * mu + 1e-5f);
    int e0 = lane * 8;
    float y[8] = {a.x,a.y,a.z,a.w,c.x,c.y,c.z,c.w};
    ushort4 o0, o1;
    o0.x = f2bf((y[0]-mu)*rstd*g[e0+0]+b[e0+0]);
    o0.y = f2bf((y[1]-mu)*rstd*g[e0+1]+b[e0+1]);
    o0.z = f2bf((y[2]-mu)*rstd*g[e0+2]+b[e0+2]);
    o0.w = f2bf((y[3]-mu)*rstd*g[e0+3]+b[e0+3]);
    o1.x = f2bf((y[4]-mu)*rstd*g[e0+4]+b[e0+4]);
    o1.y = f2bf((y[5]-mu)*rstd*g[e0+5]+b[e0+5]);
    o1.z = f2bf((y[6]-mu)*rstd*g[e0+6]+b[e0+6]);
    o1.w = f2bf((y[7]-mu)*rstd*g[e0+7]+b[e0+7]);
    *(ushort4*)&out[(size_t)row * 512 + e0]     = o0;
    *(ushort4*)&out[(size_t)row * 512 + e0 + 4] = o1;
}

// ---------------- weight transpose + cvt: Wt[n][k] = bf16(W[k][n]) ----------------
__global__ __launch_bounds__(256) void cvtT_k(const float* __restrict__ W,
                                              u16* __restrict__ Wt, int K, int N) {
    __shared__ float t[32][33];
    int k0 = blockIdx.x * 32, n0 = blockIdx.y * 32;
    int c = threadIdx.x & 31, r8 = threadIdx.x >> 5;
#pragma unroll
    for (int q = 0; q < 4; q++) {
        int r = r8 * 4 + q;
        t[r][c] = W[(size_t)(k0 + r) * N + n0 + c];
    }
    __syncthreads();
#pragma unroll
    for (int q = 0; q < 4; q++) {
        int r = r8 * 4 + q;
        Wt[(size_t)(n0 + r) * K + k0 + c] = f2bf(t[c][r]);
    }
}

// ---------------- V transpose: vt[bh][d][s] = v[b*S+s][h*256+d] ----------------
__global__ __launch_bounds__(256) void vt_k(const u16* __restrict__ v,
                                            u16* __restrict__ vt) {
    __shared__ u16 t[32][34];
    int s0 = blockIdx.x * 32, d0 = blockIdx.y * 32, bh = blockIdx.z;
    int b = bh >> 2, h = bh & 3;
    int c = threadIdx.x & 31, r4 = threadIdx.x >> 5;
#pragma unroll
    for (int q = 0; q < 4; q++) {
        int r = r4 * 4 + q;
        t[r][c] = v[(size_t)(b * 1024 + s0 + r) * I_DIM + h * 256 + d0 + c];
    }
    __syncthreads();
#pragma unroll
    for (int q = 0; q < 4; q++) {
        int r = r4 * 4 + q;
        vt[((size_t)bh * 256 + d0 + r) * 1024 + s0 + c] = t[c][r];
    }
}

// ---------------- bf16 MFMA GEMM, 2-phase dbuf + XCD swizzle ----------------
template<int EPI>
__global__ __launch_bounds__(256) void gemm_bf16_k(
    const u16* __restrict__ A, const u16* __restrict__ Wt, int N, int K,
    float* __restrict__ Cf, u16* __restrict__ Cb,
    const float* __restrict__ bias, const float* __restrict__ res, int ldres)
{
    __shared__ __align__(16) u16 As[2][128 * 32];
    __shared__ __align__(16) u16 Bs[2][128 * 32];
    int tid = threadIdx.x;
    int lane = tid & 63;
    int wm = (tid >> 6) & 1, wn = tid >> 7;
    int gx = gridDim.x;
    int nwg = gx * gridDim.y;
    int bid = blockIdx.y * gx + blockIdx.x;
    int cpx = nwg >> 3;
    int swz = (bid & 7) * cpx + (bid >> 3);
    int r0 = (swz / gx) * 128, n0 = (swz % gx) * 128;

    int arow = tid >> 2, acol = (tid & 3) * 8;
    const u16* ap0 = A  + (size_t)(r0 + arow) * K + acol;
    const u16* ap1 = A  + (size_t)(r0 + 64 + arow) * K + acol;
    const u16* bp0 = Wt + (size_t)(n0 + arow) * K + acol;
    const u16* bp1 = Wt + (size_t)(n0 + 64 + arow) * K + acol;

    auto stage = [&](int kt, int bs) {
        int koff = kt * 32;
        __builtin_amdgcn_global_load_lds((const GLOBAL_AS unsigned int*)(ap0 + koff), (LDS_AS unsigned int*)&As[bs][tid * 8], 16, 0, 0);
        __builtin_amdgcn_global_load_lds((const GLOBAL_AS unsigned int*)(ap1 + koff), (LDS_AS unsigned int*)&As[bs][2048 + tid * 8], 16, 0, 0);
        __builtin_amdgcn_global_load_lds((const GLOBAL_AS unsigned int*)(bp0 + koff), (LDS_AS unsigned int*)&Bs[bs][tid * 8], 16, 0, 0);
        __builtin_amdgcn_global_load_lds((const GLOBAL_AS unsigned int*)(bp1 + koff), (LDS_AS unsigned int*)&Bs[bs][2048 + tid * 8], 16, 0, 0);
    };

    f32x4 acc[4][4];
#pragma unroll
    for (int i = 0; i < 4; i++)
#pragma unroll
        for (int j = 0; j < 4; j++) acc[i][j] = (f32x4){0.f, 0.f, 0.f, 0.f};

    int lm = lane & 15, lk = (lane >> 4) * 8;
    int nt = K >> 5;
    stage(0, 0);
    VM0; BAR; SFENCE;
    for (int t = 0; t < nt; ++t) {
        int cur = t & 1;
        if (t + 1 < nt) stage(t + 1, cur ^ 1);
        bf16x8 af[4], bfr[4];
#pragma unroll
        for (int f = 0; f < 4; f++) {
            af[f]  = *(const bf16x8*)&As[cur][(wm * 64 + f * 16 + lm) * 32 + lk];
            bfr[f] = *(const bf16x8*)&Bs[cur][(wn * 64 + f * 16 + lm) * 32 + lk];
        }
#pragma unroll
        for (int i = 0; i < 4; i++)
#pragma unroll
            for (int j = 0; j < 4; j++)
                acc[i][j] = __builtin_amdgcn_mfma_f32_16x16x32_bf16(af[i], bfr[j], acc[i][j], 0, 0, 0);
        VM0; BAR; SFENCE;
    }
    int lr = (lane >> 4) * 4;
#pragma unroll
    for (int i = 0; i < 4; i++) {
#pragma unroll
        for (int j = 0; j < 4; j++) {
#pragma unroll
            for (int q = 0; q < 4; q++) {
                int row = r0 + wm * 64 + i * 16 + lr + q;
                int col = n0 + wn * 64 + j * 16 + lm;
                float o = acc[i][j][q];
                if (EPI == 0) {
                    Cb[(size_t)row * N + col] = f2bf(o);
                } else if (EPI == 1) {
                    if (col < 1024) Cb[(size_t)row * 1024 + col] = f2bf(o);
                    else            Cf[(size_t)row * 1024 + (col - 1024)] = o;
                } else if (EPI == 2) {
                    o += bias[col] + res[(size_t)row * ldres + col];
                    Cf[(size_t)row * N + col] = o;
                    Cb[(size_t)row * N + col] = f2bf(o);
                } else {
                    o += bias[col];
                    Cf[(size_t)row * N + col] = o;
                }
            }
        }
    }
}

// ---------------- depthwise causal conv (K=4) + bias + SiLU, bf16 in/out ----------------
__global__ __launch_bounds__(256) void conv_k(const u16* __restrict__ xm,
                                              const float* __restrict__ w,
                                              const float* __restrict__ cb,
                                              u16* __restrict__ cact) {
    int idx = blockIdx.x * 256 + threadIdx.x;
    int r = idx >> 8;
    int c = (idx & 255) * 4;
    int t = r & 1023;
    const u16* base = xm + (size_t)(r - t) * I_DIM;
    float4 acc = *(const float4*)&cb[c];
#pragma unroll
    for (int j = 0; j < 4; j++) {
        int tt = t - 3 + j;
        if (tt >= 0) {
            short4 s = *(const short4*)&base[(size_t)tt * I_DIM + c];
            float4 wv = *(const float4*)&w[j * I_DIM + c];
            acc.x = fmaf(bf2f((u16)s.x), wv.x, acc.x);
            acc.y = fmaf(bf2f((u16)s.y), wv.y, acc.y);
            acc.z = fmaf(bf2f((u16)s.z), wv.z, acc.z);
            acc.w = fmaf(bf2f((u16)s.w), wv.w, acc.w);
        }
    }
    acc.x = acc.x / (1.f + __expf(-acc.x));
    acc.y = acc.y / (1.f + __expf(-acc.y));
    acc.z = acc.z / (1.f + __expf(-acc.z));
    acc.w = acc.w / (1.f + __expf(-acc.w));
    ushort4 o;
    o.x = f2bf(acc.x); o.y = f2bf(acc.y); o.z = f2bf(acc.z); o.w = f2bf(acc.w);
    *(ushort4*)&cact[(size_t)r * I_DIM + c] = o;
}

// ---------------- i/f gate pre-activations: 4 rows/block; q/k from fused buffer ----------------
__global__ __launch_bounds__(256) void gates_k(const u16* __restrict__ qk,
                                               const u16* __restrict__ v,
                                               const float* __restrict__ wi,
                                               const float* __restrict__ bi,
                                               const float* __restrict__ wf,
                                               const float* __restrict__ bf,
                                               float* __restrict__ ipre,
                                               float* __restrict__ fpre) {
    int r0 = blockIdx.x * 4;
    int tid = threadIdx.x;
    float ai[4][4], af4[4][4];
#pragma unroll
    for (int r = 0; r < 4; r++)
#pragma unroll
        for (int m = 0; m < 4; m++) { ai[r][m] = 0.f; af4[r][m] = 0.f; }
#pragma unroll
    for (int part = 0; part < 3; part++) {
        const u16* src; size_t st;
        if (part == 0)      { src = qk + (size_t)r0 * 2048;        st = 2048; }
        else if (part == 1) { src = qk + (size_t)r0 * 2048 + 1024; st = 2048; }
        else                { src = v  + (size_t)r0 * 1024;        st = 1024; }
        const float* wip = wi + part * I_DIM * 4;
        const float* wfp = wf + part * I_DIM * 4;
#pragma unroll
        for (int jj = 0; jj < 4; jj++) {
            int e = tid + jj * 256;
            float4 w4  = *(const float4*)&wip[e * 4];
            float4 f4v = *(const float4*)&wfp[e * 4];
#pragma unroll
            for (int r = 0; r < 4; r++) {
                float xv = bf2f(src[(size_t)r * st + e]);
                ai[r][0] = fmaf(xv, w4.x, ai[r][0]);
                ai[r][1] = fmaf(xv, w4.y, ai[r][1]);
                ai[r][2] = fmaf(xv, w4.z, ai[r][2]);
                ai[r][3] = fmaf(xv, w4.w, ai[r][3]);
                af4[r][0] = fmaf(xv, f4v.x, af4[r][0]);
                af4[r][1] = fmaf(xv, f4v.y, af4[r][1]);
                af4[r][2] = fmaf(xv, f4v.z, af4[r][2]);
                af4[r][3] = fmaf(xv, f4v.w, af4[r][3]);
            }
        }
    }
#pragma unroll
    for (int off = 32; off > 0; off >>= 1) {
#pragma unroll
        for (int r = 0; r < 4; r++)
#pragma unroll
            for (int m = 0; m < 4; m++) {
                ai[r][m]  += __shfl_down(ai[r][m], off);
                af4[r][m] += __shfl_down(af4[r][m], off);
            }
    }
    __shared__ float red[4][32];
    int wv_ = tid >> 6, lane = tid & 63;
    if (lane == 0) {
#pragma unroll
        for (int r = 0; r < 4; r++)
#pragma unroll
            for (int m = 0; m < 4; m++) {
                red[wv_][r * 8 + m]     = ai[r][m];
                red[wv_][r * 8 + 4 + m] = af4[r][m];
            }
    }
    __syncthreads();
    if (tid < 32) {
        int r = tid >> 3, m = tid & 7;
        float s_ = red[0][tid] + red[1][tid] + red[2][tid] + red[3][tid];
        int row = r0 + r, bb = row >> 10, ss = row & 1023;
        if (m < 4) ipre[((size_t)(bb * 4 + m)) * 1024 + ss] = s_ + bi[m];
        else       fpre[((size_t)(bb * 4 + (m - 4))) * 1024 + ss] = s_ + bf[m - 4];
    }
}

// ---------------- parallel scan per (b,h) ----------------
__global__ __launch_bounds__(1024) void scan_k(const float* __restrict__ ipre,
                                               const float* __restrict__ fpre,
                                               float* __restrict__ cA,
                                               float* __restrict__ MA,
                                               float* __restrict__ nF) {
    __shared__ float buf[1024];
    int bh = blockIdx.x, t = threadIdx.x;
    size_t base = (size_t)bh * 1024;
    float fp = fpre[base + t];
    float lf = (fp >= 0.f) ? -log1pf(expf(-fp)) : (fp - log1pf(expf(fp)));
    buf[t] = lf; __syncthreads();
    for (int off = 1; off < 1024; off <<= 1) {
        float u = (t >= off) ? buf[t - off] : 0.f;
        __syncthreads();
        buf[t] += u;
        __syncthreads();
    }
    float lfc = buf[t];
    float c = ipre[base + t] - lfc;
    __syncthreads();
    buf[t] = c; __syncthreads();
    for (int off = 1; off < 1024; off <<= 1) {
        float u = (t >= off) ? buf[t - off] : -3.4e38f;
        __syncthreads();
        buf[t] = fmaxf(buf[t], u);
        __syncthreads();
    }
    float M = buf[t];
    cA[base + t] = c * 1.44269504f;
    MA[base + t] = M * 1.44269504f;
    nF[base + t] = expf(-(lfc + M));
}

// ---------------- MFMA causal mLSTM attention + groupnorm + gating ----------------
// 1-D grid 1024 blocks, XCD-chunked decode (one batch b per XCD) + LPT.
// t-tile 32, s-tile 32; 4 waves: wave w = (tf=w&1, sf=w>>1) for QK, d-block w*64 for PV.
__global__ __launch_bounds__(256) void attn_k(
    const u16* __restrict__ qg, const u16* __restrict__ kg, const u16* __restrict__ vt,
    const float* __restrict__ c2A, const float* __restrict__ M2A, const float* __restrict__ nFl,
    const u16* __restrict__ cact, const float* __restrict__ zb, u16* __restrict__ hb,
    const float* __restrict__ gng, const float* __restrict__ skip)
{
    __shared__ __align__(16) u16 Kb[2][32 * 256];   // K tile [s-row][512B], chunk-swizzled
    __shared__ __align__(16) u16 Ps[32 * 40];
    __shared__ float rs2[4][16];
    __shared__ float rsI[32];
    __shared__ float gS[32 * 4];
    __shared__ float gQ[32 * 4];
    __shared__ float gmu[32], gvr[32];

    int tid = threadIdx.x;
    int w = tid >> 6, l = tid & 63;
    int lm = l & 15, lk = l >> 4;
    int i0 = blockIdx.x;
    int g = (i0 & 7) * 128 + (i0 >> 3);   // XCD-chunked: XCD x gets g in [x*128, x*128+128)
    int b = g >> 7, h = (g >> 5) & 3, bx = g & 31;
    int T0 = (31 - bx) * 32;              // LPT within each XCD
    int tf = w & 1, sf = w >> 1;
    int bh32 = b * H_NUM + h;
    size_t bh = (size_t)bh32 * S_LEN;

    // Q frags (row stride 2048: fused q|k buffer)
    bf16x8 qf[8];
    {
        size_t base = ((size_t)(b * S_LEN + T0 + tf * 16 + lm)) * 2048 + h * DH_ + lk * 8;
#pragma unroll
        for (int ks = 0; ks < 8; ks++) qf[ks] = *(const bf16x8*)&qg[base + ks * 32];
    }
    f32x4 acc[2][4];
#pragma unroll
    for (int i = 0; i < 2; i++)
#pragma unroll
        for (int jd = 0; jd < 4; jd++) acc[i][jd] = (f32x4){0.f, 0.f, 0.f, 0.f};
    float rsum[4] = {0, 0, 0, 0};
    float m2r[4]; int tg[4];
#pragma unroll
    for (int q = 0; q < 4; q++) {
        tg[q] = T0 + tf * 16 + lk * 4 + q;
        m2r[q] = M2A[bh + tg[q]];
    }

    const size_t krow0 = (size_t)(b * S_LEN) * 2048 + h * DH_;
    const u16* vptr = vt + (size_t)bh32 * 256 * S_LEN + (size_t)(w * 64 + lm) * S_LEN + lk * 8;

    auto stageK = [&](int s0, int bs) {
#pragma unroll
        for (int r = 0; r < 4; r++) {
            int q = r * 256 + tid;          // 16B slot: 32 rows x 32 chunks
            int row = q >> 5, cl = q & 31;
            int cs = cl ^ (row & 7);
            const u16* src = kg + krow0 + (size_t)(s0 + row) * 2048 + cs * 8;
            __builtin_amdgcn_global_load_lds((const GLOBAL_AS unsigned int*)src,
                                             (LDS_AS unsigned int*)&Kb[bs][q * 8], 16, 0, 0);
        }
    };

    int nst = (T0 >> 5) + 1;
    // prologue
    stageK(0, 0);
    bf16x8 vA[4], vB[4];
    float c2c, c2n;
#pragma unroll
    for (int jd = 0; jd < 4; jd++) vA[jd] = *(const bf16x8*)(vptr + jd * 16 * S_LEN);
    c2c = c2A[bh + sf * 16 + lm];
    VM0; BAR; SFENCE;

    for (int st = 0; st < nst; st++) {
        int s0 = st * 32;
        int cur = st & 1;
        int more = (st + 1 < nst);
        if (more) {
            stageK(s0 + 32, cur ^ 1);
#pragma unroll
            for (int jd = 0; jd < 4; jd++) vB[jd] = *(const bf16x8*)(vptr + jd * 16 * S_LEN + s0 + 32);
            c2n = c2A[bh + s0 + 32 + sf * 16 + lm];
        }
        // ---- QK^T: wave w computes S[tf][sf] 16x16 ----
        f32x4 sacc = (f32x4){0.f, 0.f, 0.f, 0.f};
        __builtin_amdgcn_s_setprio(1);
#pragma unroll
        for (int ks = 0; ks < 8; ks++) {
            int row = sf * 16 + lm;
            int ch = (ks * 4 + lk) ^ (row & 7);
            bf16x8 kf = *(const bf16x8*)&Kb[cur][row * 256 + ch * 8];
            sacc = __builtin_amdgcn_mfma_f32_16x16x32_bf16(qf[ks], kf, sacc, 0, 0, 0);
        }
        __builtin_amdgcn_s_setprio(0);
        // ---- scale, mask, round, rowsum, stage P ----
        {
            int sg = s0 + sf * 16 + lm;
#pragma unroll
            for (int q = 0; q < 4; q++) {
                float v = sacc[q] * 0.0625f * __builtin_amdgcn_exp2f(c2c - m2r[q]);
                v = (sg <= tg[q]) ? v : 0.f;
                u16 pb = f2bf(v);
                rsum[q] += bf2f(pb);
                Ps[(tf * 16 + lk * 4 + q) * 40 + sf * 16 + lm] = pb;
            }
        }
        LGKM0; BAR; SFENCE;   // Ps visible to all waves
        // ---- PV: wave w covers d-block w*64, both t-frags ----
        __builtin_amdgcn_s_setprio(1);
#pragma unroll
        for (int i = 0; i < 2; i++) {
            bf16x8 pa = *(const bf16x8*)&Ps[(i * 16 + lm) * 40 + lk * 8];
#pragma unroll
            for (int jd = 0; jd < 4; jd++)
                acc[i][jd] = __builtin_amdgcn_mfma_f32_16x16x32_bf16(pa, vA[jd], acc[i][jd], 0, 0, 0);
        }
        __builtin_amdgcn_s_setprio(0);
        VM0; BAR; SFENCE;     // next K stage + V/c2 regs landed; Ps free
        if (more) {
#pragma unroll
            for (int jd = 0; jd < 4; jd++) vA[jd] = vB[jd];
            c2c = c2n;
        }
    }
    // ---- rowsum: reduce over lanes, then combine the two s-half waves ----
    {
#pragma unroll
        for (int m = 1; m < 16; m <<= 1) {
#pragma unroll
            for (int q = 0; q < 4; q++) rsum[q] += __shfl_xor(rsum[q], m);
        }
        if (lm == 0) {
#pragma unroll
            for (int q = 0; q < 4; q++) rs2[w][lk * 4 + q] = rsum[q];
        }
    }
    __syncthreads();
    if (tid < 32) {
        int tfi = tid >> 4, idx = tid & 15;
        float s = rs2[tfi][idx] + rs2[tfi + 2][idx];
        float n = fmaxf(fabsf(s), nFl[bh + T0 + tid]);
        rsI[tid] = 1.f / n;
    }
    __syncthreads();
    // ---- normalize + groupnorm stats (wave covers 64 of 256 d) ----
#pragma unroll
    for (int i = 0; i < 2; i++) {
#pragma unroll
        for (int q = 0; q < 4; q++) {
            int rl = i * 16 + lk * 4 + q;
            float inv = rsI[rl];
            float ps = 0.f, pq = 0.f;
#pragma unroll
            for (int jd = 0; jd < 4; jd++) {
                float v = acc[i][jd][q] * inv;
                acc[i][jd][q] = v;
                ps += v; pq += v * v;
            }
#pragma unroll
            for (int m = 1; m < 16; m <<= 1) {
                ps += __shfl_xor(ps, m);
                pq += __shfl_xor(pq, m);
            }
            if (lm == 0) { gS[rl * 4 + w] = ps; gQ[rl * 4 + w] = pq; }
        }
    }
    __syncthreads();
    if (tid < 32) {
        float s1 = gS[tid*4] + gS[tid*4+1] + gS[tid*4+2] + gS[tid*4+3];
        float s2 = gQ[tid*4] + gQ[tid*4+1] + gQ[tid*4+2] + gQ[tid*4+3];
        float mu = s1 * (1.f / 256.f);
        float var = s2 * (1.f / 256.f) - mu * mu;
        gmu[tid] = mu;
        gvr[tid] = rsqrtf(var + 1e-5f);
    }
    __syncthreads();
    // ---- epilogue ----
#pragma unroll
    for (int i = 0; i < 2; i++) {
#pragma unroll
        for (int q = 0; q < 4; q++) {
            int rl = i * 16 + lk * 4 + q;
            size_t r = (size_t)b * S_LEN + T0 + rl;
            float mu = gmu[rl], rv = gvr[rl];
#pragma unroll
            for (int jd = 0; jd < 4; jd++) {
                int cix = h * DH_ + w * 64 + jd * 16 + lm;
                float val = (acc[i][jd][q] - mu) * rv * gng[cix];
                float ca = bf2f(cact[r * I_DIM + cix]);
                float z = zb[r * I_DIM + cix];
                float hm = (val + skip[cix] * ca) * (z / (1.f + __expf(-z)));
                hb[r * I_DIM + cix] = f2bf(hm);
            }
        }
    }
}

// ---------------- host launch ----------------
extern "C" void kernel_launch(void* const* d_in, const int* in_sizes, int n_in,
                              void* d_out, int out_size, void* d_ws, size_t ws_size,
                              hipStream_t stream) {
    const float* x      = (const float*)d_in[0];
    const float* ln_g   = (const float*)d_in[1];
    const float* ln_b   = (const float*)d_in[2];
    const float* w_up   = (const float*)d_in[3];
    const float* conv_w = (const float*)d_in[4];
    const float* conv_b = (const float*)d_in[5];
    const float* wq     = (const float*)d_in[6];
    const float* wk     = (const float*)d_in[7];
    const float* wv     = (const float*)d_in[8];
    const float* w_i    = (const float*)d_in[9];
    const float* b_i    = (const float*)d_in[10];
    const float* w_f    = (const float*)d_in[11];
    const float* b_f    = (const float*)d_in[12];
    const float* skip   = (const float*)d_in[13];
    const float* gn_g   = (const float*)d_in[14];
    const float* w_down = (const float*)d_in[15];
    const float* b_down = (const float*)d_in[16];
    const float* w_fin  = (const float*)d_in[17];
    const float* b_fin  = (const float*)d_in[18];

    char* p = (char*)d_ws;
    auto alloc = [&](size_t bytes) { void* r = p; p += (bytes + 255) & ~(size_t)255; return r; };
    float* zbuf  = (float*)alloc((size_t)ROWS * 1024 * 4);
    float* xa    = (float*)alloc((size_t)ROWS * 512 * 4);
    float* xb2   = (float*)alloc((size_t)ROWS * 512 * 4);
    u16*  xln    = (u16*)alloc((size_t)ROWS * 512 * 2);
    u16*  xm     = (u16*)alloc((size_t)ROWS * 1024 * 2);
    u16*  cactb  = (u16*)alloc((size_t)ROWS * 1024 * 2);
    u16*  qkbf   = (u16*)alloc((size_t)ROWS * 2048 * 2);
    u16*  vbf    = (u16*)alloc((size_t)ROWS * 1024 * 2);
    u16*  vtg    = (u16*)alloc((size_t)32 * 256 * 1024 * 2);
    u16*  hbf    = (u16*)alloc((size_t)ROWS * 1024 * 2);
    u16*  xoutb  = (u16*)alloc((size_t)ROWS * 512 * 2);
    u16*  wupT   = (u16*)alloc((size_t)2 * 2048 * 512 * 2);
    u16*  wqkT   = (u16*)alloc((size_t)2 * 2048 * 1024 * 2);
    u16*  wvT    = (u16*)alloc((size_t)2 * 1024 * 1024 * 2);
    u16*  wdT    = (u16*)alloc((size_t)2 * 512 * 1024 * 2);
    u16*  wfT    = (u16*)alloc((size_t)128 * 512 * 2);
    float* ipre  = (float*)alloc(32768 * 4);
    float* fpre  = (float*)alloc(32768 * 4);
    float* cA    = (float*)alloc(32768 * 4);
    float* MA    = (float*)alloc(32768 * 4);
    float* nF    = (float*)alloc(32768 * 4);

    for (int l = 0; l < 2; l++) {
        cvtT_k<<<dim3(16, 64), 256, 0, stream>>>(w_up + (size_t)l * 512 * 2048, wupT + (size_t)l * 2048 * 512, 512, 2048);
        cvtT_k<<<dim3(32, 32), 256, 0, stream>>>(wq + (size_t)l * 1024 * 1024, wqkT + (size_t)l * 2048 * 1024, 1024, 1024);
        cvtT_k<<<dim3(32, 32), 256, 0, stream>>>(wk + (size_t)l * 1024 * 1024, wqkT + (size_t)l * 2048 * 1024 + 1024 * 1024, 1024, 1024);
        cvtT_k<<<dim3(32, 32), 256, 0, stream>>>(wv + (size_t)l * 1024 * 1024, wvT + (size_t)l * 1024 * 1024, 1024, 1024);
        cvtT_k<<<dim3(32, 16), 256, 0, stream>>>(w_down + (size_t)l * 1024 * 512, wdT + (size_t)l * 512 * 1024, 1024, 512);
    }
    cvtT_k<<<dim3(16, 4), 256, 0, stream>>>(w_fin, wfT, 512, 128);

    const float* xin = x;
    for (int l = 0; l < 2; l++) {
        float* xout = (l == 0) ? xa : xb2;
        ln_fused_k<<<ROWS, 64, 0, stream>>>(xin, ln_g + l * 512, ln_b + l * 512, xln);
        gemm_bf16_k<1><<<dim3(16, 64), 256, 0, stream>>>(
            xln, wupT + (size_t)l * 2048 * 512, 2048, 512, zbuf, xm, nullptr, nullptr, 0);
        conv_k<<<ROWS, 256, 0, stream>>>(xm, conv_w + l * 4 * I_DIM, conv_b + l * I_DIM, cactb);
        gemm_bf16_k<0><<<dim3(8, 64), 256, 0, stream>>>(
            xm, wvT + (size_t)l * 1024 * 1024, 1024, 1024, nullptr, vbf, nullptr, nullptr, 0);
        gemm_bf16_k<0><<<dim3(16, 64), 256, 0, stream>>>(
            cactb, wqkT + (size_t)l * 2048 * 1024, 2048, 1024, nullptr, qkbf, nullptr, nullptr, 0);
        vt_k<<<dim3(32, 8, 32), 256, 0, stream>>>(vbf, vtg);
        gates_k<<<ROWS / 4, 256, 0, stream>>>(qkbf, vbf,
            w_i + l * 3072 * 4, b_i + l * 4, w_f + l * 3072 * 4, b_f + l * 4, ipre, fpre);
        scan_k<<<32, 1024, 0, stream>>>(ipre, fpre, cA, MA, nF);
        attn_k<<<dim3(1024), 256, 0, stream>>>(qkbf, qkbf + 1024, vtg, cA, MA, nF, cactb, zbuf, hbf,
            gn_g + l * I_DIM, skip + l * I_DIM);
        gemm_bf16_k<2><<<dim3(4, 64), 256, 0, stream>>>(
            hbf, wdT + (size_t)l * 512 * 1024, 512, 1024, xout, xoutb,
            b_down + l * 512, xin, 512);
        xin = xout;
    }
    gemm_bf16_k<3><<<dim3(1, 64), 256, 0, stream>>>(
        xoutb, wfT, 128, 512, (float*)d_out, nullptr, b_fin, nullptr, 0);
}

// Round 8
// 712.291 us; speedup vs baseline: 1.0036x; 1.0036x over previous
//
#include <hip/hip_runtime.h>
#include <math.h>

#define S_LEN 1024
#define I_DIM 1024
#define DH_   256
#define H_NUM 4
#define B_NUM 8
#define ROWS  (B_NUM*S_LEN)   // 8192

#define GLOBAL_AS __attribute__((address_space(1)))
#define LDS_AS    __attribute__((address_space(3)))

#define VM0    asm volatile("s_waitcnt vmcnt(0)" ::: "memory")
#define LGKM0  asm volatile("s_waitcnt lgkmcnt(0)" ::: "memory")
#define BAR    __builtin_amdgcn_s_barrier()
#define SFENCE __builtin_amdgcn_sched_barrier(0)

typedef __attribute__((ext_vector_type(8))) short bf16x8;
typedef __attribute__((ext_vector_type(4))) float f32x4;
typedef unsigned short u16;

__device__ __forceinline__ u16 f2bf(float f) {
    union { float f; unsigned u; } v; v.f = f;
    unsigned r = v.u + 0x7FFF + ((v.u >> 16) & 1);
    return (u16)(r >> 16);
}
__device__ __forceinline__ float bf2f(u16 h) {
    union { unsigned u; float f; } v; v.u = ((unsigned)h) << 16;
    return v.f;
}

// ---------------- fused LayerNorm -> bf16 ----------------
__global__ __launch_bounds__(64) void ln_fused_k(const float* __restrict__ x,
                                                 const float* __restrict__ g,
                                                 const float* __restrict__ b,
                                                 u16* __restrict__ out) {
    int row = blockIdx.x, lane = threadIdx.x;
    const float* xr = x + (size_t)row * 512;
    float4 a = *(const float4*)&xr[lane * 8];
    float4 c = *(const float4*)&xr[lane * 8 + 4];
    float s  = a.x + a.y + a.z + a.w + c.x + c.y + c.z + c.w;
    float s2 = a.x*a.x + a.y*a.y + a.z*a.z + a.w*a.w
             + c.x*c.x + c.y*c.y + c.z*c.z + c.w*c.w;
#pragma unroll
    for (int off = 32; off > 0; off >>= 1) {
        s  += __shfl_down(s, off);
        s2 += __shfl_down(s2, off);
    }
    s = __shfl(s, 0); s2 = __shfl(s2, 0);
    float mu = s * (1.f / 512.f);
    float rstd = rsqrtf(s2 * (1.f / 512.f) - mu * mu + 1e-5f);
    int e0 = lane * 8;
    float y[8] = {a.x,a.y,a.z,a.w,c.x,c.y,c.z,c.w};
    ushort4 o0, o1;
    o0.x = f2bf((y[0]-mu)*rstd*g[e0+0]+b[e0+0]);
    o0.y = f2bf((y[1]-mu)*rstd*g[e0+1]+b[e0+1]);
    o0.z = f2bf((y[2]-mu)*rstd*g[e0+2]+b[e0+2]);
    o0.w = f2bf((y[3]-mu)*rstd*g[e0+3]+b[e0+3]);
    o1.x = f2bf((y[4]-mu)*rstd*g[e0+4]+b[e0+4]);
    o1.y = f2bf((y[5]-mu)*rstd*g[e0+5]+b[e0+5]);
    o1.z = f2bf((y[6]-mu)*rstd*g[e0+6]+b[e0+6]);
    o1.w = f2bf((y[7]-mu)*rstd*g[e0+7]+b[e0+7]);
    *(ushort4*)&out[(size_t)row * 512 + e0]     = o0;
    *(ushort4*)&out[(size_t)row * 512 + e0 + 4] = o1;
}

// ---------------- weight transpose + cvt: Wt[n][k] = bf16(W[k][n]) ----------------
__global__ __launch_bounds__(256) void cvtT_k(const float* __restrict__ W,
                                              u16* __restrict__ Wt, int K, int N) {
    __shared__ float t[32][33];
    int k0 = blockIdx.x * 32, n0 = blockIdx.y * 32;
    int c = threadIdx.x & 31, r8 = threadIdx.x >> 5;
#pragma unroll
    for (int q = 0; q < 4; q++) {
        int r = r8 * 4 + q;
        t[r][c] = W[(size_t)(k0 + r) * N + n0 + c];
    }
    __syncthreads();
#pragma unroll
    for (int q = 0; q < 4; q++) {
        int r = r8 * 4 + q;
        Wt[(size_t)(n0 + r) * K + k0 + c] = f2bf(t[c][r]);
    }
}

// ---------------- V transpose: vt[bh][d][s] = v[b*S+s][h*256+d] ----------------
__global__ __launch_bounds__(256) void vt_k(const u16* __restrict__ v,
                                            u16* __restrict__ vt) {
    __shared__ u16 t[32][34];
    int s0 = blockIdx.x * 32, d0 = blockIdx.y * 32, bh = blockIdx.z;
    int b = bh >> 2, h = bh & 3;
    int c = threadIdx.x & 31, r4 = threadIdx.x >> 5;
#pragma unroll
    for (int q = 0; q < 4; q++) {
        int r = r4 * 4 + q;
        t[r][c] = v[(size_t)(b * 1024 + s0 + r) * I_DIM + h * 256 + d0 + c];
    }
    __syncthreads();
#pragma unroll
    for (int q = 0; q < 4; q++) {
        int r = r4 * 4 + q;
        vt[((size_t)bh * 256 + d0 + r) * 1024 + s0 + c] = t[c][r];
    }
}

// ---------------- bf16 MFMA GEMM, 2-phase dbuf + XCD swizzle ----------------
template<int EPI>
__global__ __launch_bounds__(256) void gemm_bf16_k(
    const u16* __restrict__ A, const u16* __restrict__ Wt, int N, int K,
    float* __restrict__ Cf, u16* __restrict__ Cb,
    const float* __restrict__ bias, const float* __restrict__ res, int ldres)
{
    __shared__ __align__(16) u16 As[2][128 * 32];
    __shared__ __align__(16) u16 Bs[2][128 * 32];
    int tid = threadIdx.x;
    int lane = tid & 63;
    int wm = (tid >> 6) & 1, wn = tid >> 7;
    int gx = gridDim.x;
    int nwg = gx * gridDim.y;
    int bid = blockIdx.y * gx + blockIdx.x;
    int cpx = nwg >> 3;
    int swz = (bid & 7) * cpx + (bid >> 3);
    int r0 = (swz / gx) * 128, n0 = (swz % gx) * 128;

    int arow = tid >> 2, acol = (tid & 3) * 8;
    const u16* ap0 = A  + (size_t)(r0 + arow) * K + acol;
    const u16* ap1 = A  + (size_t)(r0 + 64 + arow) * K + acol;
    const u16* bp0 = Wt + (size_t)(n0 + arow) * K + acol;
    const u16* bp1 = Wt + (size_t)(n0 + 64 + arow) * K + acol;

    auto stage = [&](int kt, int bs) {
        int koff = kt * 32;
        __builtin_amdgcn_global_load_lds((const GLOBAL_AS unsigned int*)(ap0 + koff), (LDS_AS unsigned int*)&As[bs][tid * 8], 16, 0, 0);
        __builtin_amdgcn_global_load_lds((const GLOBAL_AS unsigned int*)(ap1 + koff), (LDS_AS unsigned int*)&As[bs][2048 + tid * 8], 16, 0, 0);
        __builtin_amdgcn_global_load_lds((const GLOBAL_AS unsigned int*)(bp0 + koff), (LDS_AS unsigned int*)&Bs[bs][tid * 8], 16, 0, 0);
        __builtin_amdgcn_global_load_lds((const GLOBAL_AS unsigned int*)(bp1 + koff), (LDS_AS unsigned int*)&Bs[bs][2048 + tid * 8], 16, 0, 0);
    };

    f32x4 acc[4][4];
#pragma unroll
    for (int i = 0; i < 4; i++)
#pragma unroll
        for (int j = 0; j < 4; j++) acc[i][j] = (f32x4){0.f, 0.f, 0.f, 0.f};

    int lm = lane & 15, lk = (lane >> 4) * 8;
    int nt = K >> 5;
    stage(0, 0);
    VM0; BAR; SFENCE;
    for (int t = 0; t < nt; ++t) {
        int cur = t & 1;
        if (t + 1 < nt) stage(t + 1, cur ^ 1);
        bf16x8 af[4], bfr[4];
#pragma unroll
        for (int f = 0; f < 4; f++) {
            af[f]  = *(const bf16x8*)&As[cur][(wm * 64 + f * 16 + lm) * 32 + lk];
            bfr[f] = *(const bf16x8*)&Bs[cur][(wn * 64 + f * 16 + lm) * 32 + lk];
        }
#pragma unroll
        for (int i = 0; i < 4; i++)
#pragma unroll
            for (int j = 0; j < 4; j++)
                acc[i][j] = __builtin_amdgcn_mfma_f32_16x16x32_bf16(af[i], bfr[j], acc[i][j], 0, 0, 0);
        VM0; BAR; SFENCE;
    }
    int lr = (lane >> 4) * 4;
#pragma unroll
    for (int i = 0; i < 4; i++) {
#pragma unroll
        for (int j = 0; j < 4; j++) {
#pragma unroll
            for (int q = 0; q < 4; q++) {
                int row = r0 + wm * 64 + i * 16 + lr + q;
                int col = n0 + wn * 64 + j * 16 + lm;
                float o = acc[i][j][q];
                if (EPI == 0) {
                    Cb[(size_t)row * N + col] = f2bf(o);
                } else if (EPI == 1) {
                    if (col < 1024) Cb[(size_t)row * 1024 + col] = f2bf(o);
                    else            Cf[(size_t)row * 1024 + (col - 1024)] = o;
                } else if (EPI == 2) {
                    o += bias[col] + res[(size_t)row * ldres + col];
                    Cf[(size_t)row * N + col] = o;
                    Cb[(size_t)row * N + col] = f2bf(o);
                } else {
                    o += bias[col];
                    Cf[(size_t)row * N + col] = o;
                }
            }
        }
    }
}

// ---------------- depthwise causal conv (K=4) + bias + SiLU, bf16 in/out ----------------
__global__ __launch_bounds__(256) void conv_k(const u16* __restrict__ xm,
                                              const float* __restrict__ w,
                                              const float* __restrict__ cb,
                                              u16* __restrict__ cact) {
    int idx = blockIdx.x * 256 + threadIdx.x;
    int r = idx >> 8;
    int c = (idx & 255) * 4;
    int t = r & 1023;
    const u16* base = xm + (size_t)(r - t) * I_DIM;
    float4 acc = *(const float4*)&cb[c];
#pragma unroll
    for (int j = 0; j < 4; j++) {
        int tt = t - 3 + j;
        if (tt >= 0) {
            short4 s = *(const short4*)&base[(size_t)tt * I_DIM + c];
            float4 wv = *(const float4*)&w[j * I_DIM + c];
            acc.x = fmaf(bf2f((u16)s.x), wv.x, acc.x);
            acc.y = fmaf(bf2f((u16)s.y), wv.y, acc.y);
            acc.z = fmaf(bf2f((u16)s.z), wv.z, acc.z);
            acc.w = fmaf(bf2f((u16)s.w), wv.w, acc.w);
        }
    }
    acc.x = acc.x / (1.f + __expf(-acc.x));
    acc.y = acc.y / (1.f + __expf(-acc.y));
    acc.z = acc.z / (1.f + __expf(-acc.z));
    acc.w = acc.w / (1.f + __expf(-acc.w));
    ushort4 o;
    o.x = f2bf(acc.x); o.y = f2bf(acc.y); o.z = f2bf(acc.z); o.w = f2bf(acc.w);
    *(ushort4*)&cact[(size_t)r * I_DIM + c] = o;
}

// ---------------- i/f gate pre-activations: 4 rows/block; q/k from fused buffer ----------------
__global__ __launch_bounds__(256) void gates_k(const u16* __restrict__ qk,
                                               const u16* __restrict__ v,
                                               const float* __restrict__ wi,
                                               const float* __restrict__ bi,
                                               const float* __restrict__ wf,
                                               const float* __restrict__ bf,
                                               float* __restrict__ ipre,
                                               float* __restrict__ fpre) {
    int r0 = blockIdx.x * 4;
    int tid = threadIdx.x;
    float ai[4][4], af4[4][4];
#pragma unroll
    for (int r = 0; r < 4; r++)
#pragma unroll
        for (int m = 0; m < 4; m++) { ai[r][m] = 0.f; af4[r][m] = 0.f; }
#pragma unroll
    for (int part = 0; part < 3; part++) {
        const u16* src; size_t st;
        if (part == 0)      { src = qk + (size_t)r0 * 2048;        st = 2048; }
        else if (part == 1) { src = qk + (size_t)r0 * 2048 + 1024; st = 2048; }
        else                { src = v  + (size_t)r0 * 1024;        st = 1024; }
        const float* wip = wi + part * I_DIM * 4;
        const float* wfp = wf + part * I_DIM * 4;
#pragma unroll
        for (int jj = 0; jj < 4; jj++) {
            int e = tid + jj * 256;
            float4 w4  = *(const float4*)&wip[e * 4];
            float4 f4v = *(const float4*)&wfp[e * 4];
#pragma unroll
            for (int r = 0; r < 4; r++) {
                float xv = bf2f(src[(size_t)r * st + e]);
                ai[r][0] = fmaf(xv, w4.x, ai[r][0]);
                ai[r][1] = fmaf(xv, w4.y, ai[r][1]);
                ai[r][2] = fmaf(xv, w4.z, ai[r][2]);
                ai[r][3] = fmaf(xv, w4.w, ai[r][3]);
                af4[r][0] = fmaf(xv, f4v.x, af4[r][0]);
                af4[r][1] = fmaf(xv, f4v.y, af4[r][1]);
                af4[r][2] = fmaf(xv, f4v.z, af4[r][2]);
                af4[r][3] = fmaf(xv, f4v.w, af4[r][3]);
            }
        }
    }
#pragma unroll
    for (int off = 32; off > 0; off >>= 1) {
#pragma unroll
        for (int r = 0; r < 4; r++)
#pragma unroll
            for (int m = 0; m < 4; m++) {
                ai[r][m]  += __shfl_down(ai[r][m], off);
                af4[r][m] += __shfl_down(af4[r][m], off);
            }
    }
    __shared__ float red[4][32];
    int wv_ = tid >> 6, lane = tid & 63;
    if (lane == 0) {
#pragma unroll
        for (int r = 0; r < 4; r++)
#pragma unroll
            for (int m = 0; m < 4; m++) {
                red[wv_][r * 8 + m]     = ai[r][m];
                red[wv_][r * 8 + 4 + m] = af4[r][m];
            }
    }
    __syncthreads();
    if (tid < 32) {
        int r = tid >> 3, m = tid & 7;
        float s_ = red[0][tid] + red[1][tid] + red[2][tid] + red[3][tid];
        int row = r0 + r, bb = row >> 10, ss = row & 1023;
        if (m < 4) ipre[((size_t)(bb * 4 + m)) * 1024 + ss] = s_ + bi[m];
        else       fpre[((size_t)(bb * 4 + (m - 4))) * 1024 + ss] = s_ + bf[m - 4];
    }
}

// ---------------- parallel scan per (b,h) ----------------
__global__ __launch_bounds__(1024) void scan_k(const float* __restrict__ ipre,
                                               const float* __restrict__ fpre,
                                               float* __restrict__ cA,
                                               float* __restrict__ MA,
                                               float* __restrict__ nF) {
    __shared__ float buf[1024];
    int bh = blockIdx.x, t = threadIdx.x;
    size_t base = (size_t)bh * 1024;
    float fp = fpre[base + t];
    float lf = (fp >= 0.f) ? -log1pf(expf(-fp)) : (fp - log1pf(expf(fp)));
    buf[t] = lf; __syncthreads();
    for (int off = 1; off < 1024; off <<= 1) {
        float u = (t >= off) ? buf[t - off] : 0.f;
        __syncthreads();
        buf[t] += u;
        __syncthreads();
    }
    float lfc = buf[t];
    float c = ipre[base + t] - lfc;
    __syncthreads();
    buf[t] = c; __syncthreads();
    for (int off = 1; off < 1024; off <<= 1) {
        float u = (t >= off) ? buf[t - off] : -3.4e38f;
        __syncthreads();
        buf[t] = fmaxf(buf[t], u);
        __syncthreads();
    }
    float M = buf[t];
    cA[base + t] = c * 1.44269504f;
    MA[base + t] = M * 1.44269504f;
    nF[base + t] = expf(-(lfc + M));
}

// ---------------- MFMA causal mLSTM attention + groupnorm + gating ----------------
// 1-D grid 1024 blocks, XCD-chunked decode + LPT. t-tile 32, s-tile 32.
// Skewed pipeline, ONE barrier per tile:
//   stage K(t+1) | issue V(t)/c2(t+1) | QK(t) | scale->Ps[t&1] | PV(t-1) from Ps[(t-1)&1]
//   | swap regs (auto-waits vB => K loads also retired, FIFO) | LGKM | s_barrier
__global__ __launch_bounds__(256) void attn_k(
    const u16* __restrict__ qg, const u16* __restrict__ kg, const u16* __restrict__ vt,
    const float* __restrict__ c2A, const float* __restrict__ M2A, const float* __restrict__ nFl,
    const u16* __restrict__ cact, const float* __restrict__ zb, u16* __restrict__ hb,
    const float* __restrict__ gng, const float* __restrict__ skip)
{
    __shared__ __align__(16) u16 Kb[2][32 * 256];   // K tile [s-row][512B], chunk-swizzled
    __shared__ __align__(16) u16 Ps[2][32 * 40];    // P double-buffered
    __shared__ float rs2[4][16];
    __shared__ float rsI[32];
    __shared__ float gS[32 * 4];
    __shared__ float gQ[32 * 4];
    __shared__ float gmu[32], gvr[32];

    int tid = threadIdx.x;
    int w = tid >> 6, l = tid & 63;
    int lm = l & 15, lk = l >> 4;
    int i0 = blockIdx.x;
    int g = (i0 & 7) * 128 + (i0 >> 3);   // XCD-chunked: XCD x owns batch x
    int b = g >> 7, h = (g >> 5) & 3, bx = g & 31;
    int T0 = (31 - bx) * 32;              // LPT within each XCD
    int tf = w & 1, sf = w >> 1;
    int bh32 = b * H_NUM + h;
    size_t bh = (size_t)bh32 * S_LEN;

    // Q frags (row stride 2048: fused q|k buffer)
    bf16x8 qf[8];
    {
        size_t base = ((size_t)(b * S_LEN + T0 + tf * 16 + lm)) * 2048 + h * DH_ + lk * 8;
#pragma unroll
        for (int ks = 0; ks < 8; ks++) qf[ks] = *(const bf16x8*)&qg[base + ks * 32];
    }
    f32x4 acc[2][4];
#pragma unroll
    for (int i = 0; i < 2; i++)
#pragma unroll
        for (int jd = 0; jd < 4; jd++) acc[i][jd] = (f32x4){0.f, 0.f, 0.f, 0.f};
    float rsum[4] = {0, 0, 0, 0};
    float m2r[4]; int tg[4];
#pragma unroll
    for (int q = 0; q < 4; q++) {
        tg[q] = T0 + tf * 16 + lk * 4 + q;
        m2r[q] = M2A[bh + tg[q]];
    }

    const size_t krow0 = (size_t)(b * S_LEN) * 2048 + h * DH_;
    const u16* vptr = vt + (size_t)bh32 * 256 * S_LEN + (size_t)(w * 64 + lm) * S_LEN + lk * 8;

    auto stageK = [&](int s0, int bs) {
#pragma unroll
        for (int r = 0; r < 4; r++) {
            int q = r * 256 + tid;          // 16B slot: 32 rows x 32 chunks
            int row = q >> 5, cl = q & 31;
            int cs = cl ^ (row & 7);
            const u16* src = kg + krow0 + (size_t)(s0 + row) * 2048 + cs * 8;
            __builtin_amdgcn_global_load_lds((const GLOBAL_AS unsigned int*)src,
                                             (LDS_AS unsigned int*)&Kb[bs][q * 8], 16, 0, 0);
        }
    };

    int nst = (T0 >> 5) + 1;
    stageK(0, 0);
    bf16x8 vA[4], vB[4];
    float c2c, c2n;
    c2c = c2A[bh + sf * 16 + lm];
    VM0; BAR; SFENCE;

    for (int t = 0; t <= nst; t++) {
        int s0 = t * 32;
        int kc = t & 1;
        bool qp = (t < nst);
        bool more = (t + 1 < nst);
        if (qp) {
            if (more) stageK(s0 + 32, kc ^ 1);
            SFENCE;   // pin: K stage loads issue before V/c2 loads (FIFO count)
            // V(t) for next iteration's PV
#pragma unroll
            for (int jd = 0; jd < 4; jd++) vB[jd] = *(const bf16x8*)(vptr + jd * 16 * S_LEN + s0);
            if (more) c2n = c2A[bh + s0 + 32 + sf * 16 + lm];
            // ---- QK^T: wave w computes S[tf][sf] 16x16 from Kb[kc] ----
            f32x4 sacc = (f32x4){0.f, 0.f, 0.f, 0.f};
            __builtin_amdgcn_s_setprio(1);
#pragma unroll
            for (int ks = 0; ks < 8; ks++) {
                int row = sf * 16 + lm;
                int ch = (ks * 4 + lk) ^ (row & 7);
                bf16x8 kf = *(const bf16x8*)&Kb[kc][row * 256 + ch * 8];
                sacc = __builtin_amdgcn_mfma_f32_16x16x32_bf16(qf[ks], kf, sacc, 0, 0, 0);
            }
            __builtin_amdgcn_s_setprio(0);
            // ---- scale, mask, round, rowsum, stage P -> Ps[kc] ----
            int sg = s0 + sf * 16 + lm;
#pragma unroll
            for (int q = 0; q < 4; q++) {
                float v = sacc[q] * 0.0625f * __builtin_amdgcn_exp2f(c2c - m2r[q]);
                v = (sg <= tg[q]) ? v : 0.f;
                u16 pb = f2bf(v);
                rsum[q] += bf2f(pb);
                Ps[kc][(tf * 16 + lk * 4 + q) * 40 + sf * 16 + lm] = pb;
            }
        }
        if (t > 0) {
            // ---- PV(t-1): Ps[kc^1] x vA (=V(t-1)); wave w covers d-block w*64 ----
            __builtin_amdgcn_s_setprio(1);
#pragma unroll
            for (int i = 0; i < 2; i++) {
                bf16x8 pa = *(const bf16x8*)&Ps[kc ^ 1][(i * 16 + lm) * 40 + lk * 8];
#pragma unroll
                for (int jd = 0; jd < 4; jd++)
                    acc[i][jd] = __builtin_amdgcn_mfma_f32_16x16x32_bf16(pa, vA[jd], acc[i][jd], 0, 0, 0);
            }
            __builtin_amdgcn_s_setprio(0);
        }
        if (qp) {
            // swap: auto vmcnt-wait on vB/c2n => all this-iter loads (K first) retired
#pragma unroll
            for (int jd = 0; jd < 4; jd++) vA[jd] = vB[jd];
            if (more) c2c = c2n;
        }
        LGKM0; BAR; SFENCE;
    }
    // ---- rowsum: reduce over lanes, then combine the two s-half waves ----
    {
#pragma unroll
        for (int m = 1; m < 16; m <<= 1) {
#pragma unroll
            for (int q = 0; q < 4; q++) rsum[q] += __shfl_xor(rsum[q], m);
        }
        if (lm == 0) {
#pragma unroll
            for (int q = 0; q < 4; q++) rs2[w][lk * 4 + q] = rsum[q];
        }
    }
    __syncthreads();
    if (tid < 32) {
        int tfi = tid >> 4, idx = tid & 15;
        float s = rs2[tfi][idx] + rs2[tfi + 2][idx];
        float n = fmaxf(fabsf(s), nFl[bh + T0 + tid]);
        rsI[tid] = 1.f / n;
    }
    __syncthreads();
    // ---- normalize + groupnorm stats (wave covers 64 of 256 d) ----
#pragma unroll
    for (int i = 0; i < 2; i++) {
#pragma unroll
        for (int q = 0; q < 4; q++) {
            int rl = i * 16 + lk * 4 + q;
            float inv = rsI[rl];
            float ps = 0.f, pq = 0.f;
#pragma unroll
            for (int jd = 0; jd < 4; jd++) {
                float v = acc[i][jd][q] * inv;
                acc[i][jd][q] = v;
                ps += v; pq += v * v;
            }
#pragma unroll
            for (int m = 1; m < 16; m <<= 1) {
                ps += __shfl_xor(ps, m);
                pq += __shfl_xor(pq, m);
            }
            if (lm == 0) { gS[rl * 4 + w] = ps; gQ[rl * 4 + w] = pq; }
        }
    }
    __syncthreads();
    if (tid < 32) {
        float s1 = gS[tid*4] + gS[tid*4+1] + gS[tid*4+2] + gS[tid*4+3];
        float s2 = gQ[tid*4] + gQ[tid*4+1] + gQ[tid*4+2] + gQ[tid*4+3];
        float mu = s1 * (1.f / 256.f);
        float var = s2 * (1.f / 256.f) - mu * mu;
        gmu[tid] = mu;
        gvr[tid] = rsqrtf(var + 1e-5f);
    }
    __syncthreads();
    // ---- epilogue ----
#pragma unroll
    for (int i = 0; i < 2; i++) {
#pragma unroll
        for (int q = 0; q < 4; q++) {
            int rl = i * 16 + lk * 4 + q;
            size_t r = (size_t)b * S_LEN + T0 + rl;
            float mu = gmu[rl], rv = gvr[rl];
#pragma unroll
            for (int jd = 0; jd < 4; jd++) {
                int cix = h * DH_ + w * 64 + jd * 16 + lm;
                float val = (acc[i][jd][q] - mu) * rv * gng[cix];
                float ca = bf2f(cact[r * I_DIM + cix]);
                float z = zb[r * I_DIM + cix];
                float hm = (val + skip[cix] * ca) * (z / (1.f + __expf(-z)));
                hb[r * I_DIM + cix] = f2bf(hm);
            }
        }
    }
}

// ---------------- host launch ----------------
extern "C" void kernel_launch(void* const* d_in, const int* in_sizes, int n_in,
                              void* d_out, int out_size, void* d_ws, size_t ws_size,
                              hipStream_t stream) {
    const float* x      = (const float*)d_in[0];
    const float* ln_g   = (const float*)d_in[1];
    const float* ln_b   = (const float*)d_in[2];
    const float* w_up   = (const float*)d_in[3];
    const float* conv_w = (const float*)d_in[4];
    const float* conv_b = (const float*)d_in[5];
    const float* wq     = (const float*)d_in[6];
    const float* wk     = (const float*)d_in[7];
    const float* wv     = (const float*)d_in[8];
    const float* w_i    = (const float*)d_in[9];
    const float* b_i    = (const float*)d_in[10];
    const float* w_f    = (const float*)d_in[11];
    const float* b_f    = (const float*)d_in[12];
    const float* skip   = (const float*)d_in[13];
    const float* gn_g   = (const float*)d_in[14];
    const float* w_down = (const float*)d_in[15];
    const float* b_down = (const float*)d_in[16];
    const float* w_fin  = (const float*)d_in[17];
    const float* b_fin  = (const float*)d_in[18];

    char* p = (char*)d_ws;
    auto alloc = [&](size_t bytes) { void* r = p; p += (bytes + 255) & ~(size_t)255; return r; };
    float* zbuf  = (float*)alloc((size_t)ROWS * 1024 * 4);
    float* xa    = (float*)alloc((size_t)ROWS * 512 * 4);
    float* xb2   = (float*)alloc((size_t)ROWS * 512 * 4);
    u16*  xln    = (u16*)alloc((size_t)ROWS * 512 * 2);
    u16*  xm     = (u16*)alloc((size_t)ROWS * 1024 * 2);
    u16*  cactb  = (u16*)alloc((size_t)ROWS * 1024 * 2);
    u16*  qkbf   = (u16*)alloc((size_t)ROWS * 2048 * 2);
    u16*  vbf    = (u16*)alloc((size_t)ROWS * 1024 * 2);
    u16*  vtg    = (u16*)alloc((size_t)32 * 256 * 1024 * 2);
    u16*  hbf    = (u16*)alloc((size_t)ROWS * 1024 * 2);
    u16*  xoutb  = (u16*)alloc((size_t)ROWS * 512 * 2);
    u16*  wupT   = (u16*)alloc((size_t)2 * 2048 * 512 * 2);
    u16*  wqkT   = (u16*)alloc((size_t)2 * 2048 * 1024 * 2);
    u16*  wvT    = (u16*)alloc((size_t)2 * 1024 * 1024 * 2);
    u16*  wdT    = (u16*)alloc((size_t)2 * 512 * 1024 * 2);
    u16*  wfT    = (u16*)alloc((size_t)128 * 512 * 2);
    float* ipre  = (float*)alloc(32768 * 4);
    float* fpre  = (float*)alloc(32768 * 4);
    float* cA    = (float*)alloc(32768 * 4);
    float* MA    = (float*)alloc(32768 * 4);
    float* nF    = (float*)alloc(32768 * 4);

    for (int l = 0; l < 2; l++) {
        cvtT_k<<<dim3(16, 64), 256, 0, stream>>>(w_up + (size_t)l * 512 * 2048, wupT + (size_t)l * 2048 * 512, 512, 2048);
        cvtT_k<<<dim3(32, 32), 256, 0, stream>>>(wq + (size_t)l * 1024 * 1024, wqkT + (size_t)l * 2048 * 1024, 1024, 1024);
        cvtT_k<<<dim3(32, 32), 256, 0, stream>>>(wk + (size_t)l * 1024 * 1024, wqkT + (size_t)l * 2048 * 1024 + 1024 * 1024, 1024, 1024);
        cvtT_k<<<dim3(32, 32), 256, 0, stream>>>(wv + (size_t)l * 1024 * 1024, wvT + (size_t)l * 1024 * 1024, 1024, 1024);
        cvtT_k<<<dim3(32, 16), 256, 0, stream>>>(w_down + (size_t)l * 1024 * 512, wdT + (size_t)l * 512 * 1024, 1024, 512);
    }
    cvtT_k<<<dim3(16, 4), 256, 0, stream>>>(w_fin, wfT, 512, 128);

    const float* xin = x;
    for (int l = 0; l < 2; l++) {
        float* xout = (l == 0) ? xa : xb2;
        ln_fused_k<<<ROWS, 64, 0, stream>>>(xin, ln_g + l * 512, ln_b + l * 512, xln);
        gemm_bf16_k<1><<<dim3(16, 64), 256, 0, stream>>>(
            xln, wupT + (size_t)l * 2048 * 512, 2048, 512, zbuf, xm, nullptr, nullptr, 0);
        conv_k<<<ROWS, 256, 0, stream>>>(xm, conv_w + l * 4 * I_DIM, conv_b + l * I_DIM, cactb);
        gemm_bf16_k<0><<<dim3(8, 64), 256, 0, stream>>>(
            xm, wvT + (size_t)l * 1024 * 1024, 1024, 1024, nullptr, vbf, nullptr, nullptr, 0);
        gemm_bf16_k<0><<<dim3(16, 64), 256, 0, stream>>>(
            cactb, wqkT + (size_t)l * 2048 * 1024, 2048, 1024, nullptr, qkbf, nullptr, nullptr, 0);
        vt_k<<<dim3(32, 8, 32), 256, 0, stream>>>(vbf, vtg);
        gates_k<<<ROWS / 4, 256, 0, stream>>>(qkbf, vbf,
            w_i + l * 3072 * 4, b_i + l * 4, w_f + l * 3072 * 4, b_f + l * 4, ipre, fpre);
        scan_k<<<32, 1024, 0, stream>>>(ipre, fpre, cA, MA, nF);
        attn_k<<<dim3(1024), 256, 0, stream>>>(qkbf, qkbf + 1024, vtg, cA, MA, nF, cactb, zbuf, hbf,
            gn_g + l * I_DIM, skip + l * I_DIM);
        gemm_bf16_k<2><<<dim3(4, 64), 256, 0, stream>>>(
            hbf, wdT + (size_t)l * 512 * 1024, 512, 1024, xout, xoutb,
            b_down + l * 512, xin, 512);
        xin = xout;
    }
    gemm_bf16_k<3><<<dim3(1, 64), 256, 0, stream>>>(
        xoutb, wfT, 128, 512, (float*)d_out, nullptr, b_fin, nullptr, 0);
}